// Round 6
// baseline (216.038 us; speedup 1.0000x reference)
//
#include <hip/hip_runtime.h>

// Problem constants
#define LSEQ 1024
#define DMODEL 1024
#define NHEADS 16
#define FDIM 16
#define HDIM 64
#define DFEAT 273          // 1 + 16 + 256
#define CHUNK 64
#define NCHUNK 16
#define KPD 288            // kvp (fp32 partials) row stride
#define KVTP 296           // kvS LDS row stride (592B -> 2-way banks, free)
#define C2F 0.17677669529663687f   // 1/(4*sqrt(2))

typedef __attribute__((ext_vector_type(8))) short short8;   // 8 bf16 (4 VGPRs)
typedef __attribute__((ext_vector_type(4))) float floatx4;  // MFMA acc

__device__ __forceinline__ float bf2f(unsigned short u) {
    unsigned int x = ((unsigned int)u) << 16;
    return __builtin_bit_cast(float, x);
}
__device__ __forceinline__ unsigned short f2bf(float f) {
    unsigned int x = __builtin_bit_cast(unsigned int, f);
    unsigned int r = (x + 0x7fffu + ((x >> 16) & 1u)) >> 16;
    return (unsigned short)r;
}

// Per-block dtype detector: samples 1024 ushorts of Wq. bf16 data -> exponents
// cluster tightly (bad ~0%); fp32-as-ushort -> half the samples are uniform
// mantissa bits (bad ~30%+). Returns 1 if inputs are fp32.
__device__ __forceinline__ int block_detect_fp32(const unsigned short* wq) {
    __shared__ int cnt;
    if (threadIdx.x == 0) cnt = 0;
    __syncthreads();
    int bad = 0;
    for (int i = threadIdx.x; i < 1024; i += blockDim.x) {
        int e = (wq[i] >> 7) & 0xFF;
        if (e >= 143 || (e > 0 && e <= 80)) bad++;
    }
    if (bad) atomicAdd(&cnt, bad);
    __syncthreads();
    return cnt > 128;
}

// Workspace layout (ushort indices):
//   qbB @0        (262144)   bf16 q  [1024][256]
//   kbB @262144   (262144)   bf16 k  [1024][256]
//   vbB @524288   (1048576)  bf16 v  [1024][1024]
//   ybB @1572864  (1048576)  bf16 y  [1024][1024]
// float region F0 = 1310720 (float idx):
//   kvp @F0       (4792320)  fp32 KV chunk partials [h][c][65][288]
#define U_QB   0
#define U_KB   262144
#define U_VB   524288
#define U_YB   1572864
#define F_KVP  1310720

// ---------------------------------------------------------------------------
// MFMA helper
// ---------------------------------------------------------------------------
#define MFMA(a, b, c) __builtin_amdgcn_mfma_f32_16x16x32_bf16((a), (b), (c), 0, 0, 0)

// ---------------------------------------------------------------------------
// Kernel 1: QKV projection, LDS-staged bf16 MFMA GEMM, dual input dtype.
// C = hid @ [Wq;Wk;Wv]^T. 64x64 C-tile/block, BK=128, 8 K-iters.
// grid.x: 0..3 -> q, 4..7 -> k, 8..23 -> v. grid.y = row tile (16).
// 4 waves in 2x2; each wave 32x32 (2x2 MFMA tiles), 16 MFMA per K-iter.
// ---------------------------------------------------------------------------
__global__ __launch_bounds__(256) void qkv_gemm(
    const void* __restrict__ hidR, const void* __restrict__ WqR,
    const void* __restrict__ WkR, const void* __restrict__ WvR,
    unsigned short* __restrict__ qb, unsigned short* __restrict__ kb,
    unsigned short* __restrict__ vb) {
    int fp32 = block_detect_fp32((const unsigned short*)WqR);
    __shared__ __align__(16) unsigned short As[64][136];
    __shared__ __align__(16) unsigned short Bs[64][136];
    int nb = blockIdx.x, mb = blockIdx.y;
    const void* Braw; unsigned short* Cout; int ldc, col0, br0;
    if (nb < 4)      { Braw = WqR; br0 = nb * 64;       Cout = qb; ldc = 256;  col0 = nb * 64; }
    else if (nb < 8) { Braw = WkR; br0 = (nb - 4) * 64; Cout = kb; ldc = 256;  col0 = (nb - 4) * 64; }
    else             { Braw = WvR; br0 = (nb - 8) * 64; Cout = vb; ldc = 1024; col0 = (nb - 8) * 64; }

    int t = threadIdx.x;
    int r = t >> 2, c0 = (t & 3) * 32;           // staging: row, col-segment
    int wave = t >> 6, lane = t & 63;
    int ml = lane & 15, q4 = lane >> 4;
    int mq = (wave >> 1) * 32, nq = (wave & 1) * 32;
    floatx4 acc00 = {0.f,0.f,0.f,0.f}, acc01 = acc00, acc10 = acc00, acc11 = acc00;

    for (int k0 = 0; k0 < DMODEL; k0 += 128) {
        short8 av[4], bv[4];
        if (!fp32) {
            const unsigned short* Ap = (const unsigned short*)hidR + (size_t)(mb * 64 + r) * DMODEL + k0 + c0;
            const unsigned short* Bp = (const unsigned short*)Braw + (size_t)(br0 + r) * DMODEL + k0 + c0;
            #pragma unroll
            for (int j = 0; j < 4; ++j) {
                av[j] = *(const short8*)(Ap + j * 8);
                bv[j] = *(const short8*)(Bp + j * 8);
            }
        } else {
            const float* Ap = (const float*)hidR + (size_t)(mb * 64 + r) * DMODEL + k0 + c0;
            const float* Bp = (const float*)Braw + (size_t)(br0 + r) * DMODEL + k0 + c0;
            #pragma unroll
            for (int j = 0; j < 4; ++j) {
                #pragma unroll
                for (int u = 0; u < 8; ++u) {
                    av[j][u] = (short)f2bf(Ap[j * 8 + u]);
                    bv[j][u] = (short)f2bf(Bp[j * 8 + u]);
                }
            }
        }
        __syncthreads();   // previous iter's LDS reads done
        #pragma unroll
        for (int j = 0; j < 4; ++j) {
            *(short8*)&As[r][c0 + j * 8] = av[j];
            *(short8*)&Bs[r][c0 + j * 8] = bv[j];
        }
        __syncthreads();
        #pragma unroll
        for (int kk = 0; kk < 4; ++kk) {
            short8 a0 = *(const short8*)&As[mq + ml][kk * 32 + q4 * 8];
            short8 a1 = *(const short8*)&As[mq + 16 + ml][kk * 32 + q4 * 8];
            short8 b0 = *(const short8*)&Bs[nq + ml][kk * 32 + q4 * 8];
            short8 b1 = *(const short8*)&Bs[nq + 16 + ml][kk * 32 + q4 * 8];
            acc00 = MFMA(a0, b0, acc00); acc01 = MFMA(a0, b1, acc01);
            acc10 = MFMA(a1, b0, acc10); acc11 = MFMA(a1, b1, acc11);
        }
    }
    #pragma unroll
    for (int mi = 0; mi < 2; ++mi) {
        #pragma unroll
        for (int ni = 0; ni < 2; ++ni) {
            floatx4 acc = mi == 0 ? (ni == 0 ? acc00 : acc01) : (ni == 0 ? acc10 : acc11);
            int nloc = nq + ni * 16 + ml;
            #pragma unroll
            for (int r4 = 0; r4 < 4; ++r4) {
                int row = mb * 64 + mq + mi * 16 + q4 * 4 + r4;
                Cout[(size_t)row * ldc + col0 + nloc] = f2bf(acc[r4]);
            }
        }
    }
}

// ---------------------------------------------------------------------------
// Kernel 2: per (head, chunk) KV partials, TRANSPOSED: kvp[h][c][dd][D],
// dd in [0,65) (64 = ones/den row), D-contiguous rows (stride 288).
// ---------------------------------------------------------------------------
__global__ __launch_bounds__(320) void chunk_kv(
    const unsigned short* __restrict__ kb, const unsigned short* __restrict__ vb,
    float* __restrict__ kvp) {
    int h = blockIdx.x & 15, c = blockIdx.x >> 4;
    int l0 = c * CHUNK;
    __shared__ __align__(16) float ks[64][16];
    __shared__ __align__(16) float vs[64][64];
    int t = threadIdx.x;
    if (t < 256) {
        int m = t >> 2, i4 = (t & 3) * 4;
        ushort4 a = *(const ushort4*)&kb[(size_t)(l0 + m) * 256 + h * 16 + i4];
        ks[m][i4] = bf2f(a.x); ks[m][i4 + 1] = bf2f(a.y);
        ks[m][i4 + 2] = bf2f(a.z); ks[m][i4 + 3] = bf2f(a.w);
        int d16 = (t & 3) * 16;
        #pragma unroll
        for (int u = 0; u < 4; ++u) {
            ushort4 b = *(const ushort4*)&vb[(size_t)(l0 + m) * 1024 + h * 64 + d16 + u * 4];
            vs[m][d16 + u * 4]     = bf2f(b.x);
            vs[m][d16 + u * 4 + 1] = bf2f(b.y);
            vs[m][d16 + u * 4 + 2] = bf2f(b.z);
            vs[m][d16 + u * 4 + 3] = bf2f(b.w);
        }
    }
    __syncthreads();

    size_t base = (size_t)(h * NCHUNK + c) * 65 * KPD;
    if (t < 256) {
        int d = t & 63, g = t >> 6;
        float accq[4][16] = {};
        float accl[4] = {};
        float accc = 0.f;
        for (int tt = 0; tt < 64; ++tt) {
            float w = vs[tt][d];
            float4 ki = *(const float4*)&ks[tt][g * 4];
            float kj[16];
            #pragma unroll
            for (int u = 0; u < 4; ++u) {
                float4 kk4 = *(const float4*)&ks[tt][u * 4];
                kj[u * 4 + 0] = kk4.x; kj[u * 4 + 1] = kk4.y; kj[u * 4 + 2] = kk4.z; kj[u * 4 + 3] = kk4.w;
            }
            float p0 = ki.x * w, p1 = ki.y * w, p2 = ki.z * w, p3 = ki.w * w;
            #pragma unroll
            for (int j = 0; j < 16; ++j) {
                accq[0][j] += p0 * kj[j];
                accq[1][j] += p1 * kj[j];
                accq[2][j] += p2 * kj[j];
                accq[3][j] += p3 * kj[j];
            }
            accl[0] += p0; accl[1] += p1; accl[2] += p2; accl[3] += p3;
            if (g == 0) accc += w;
        }
        float* rowp = kvp + base + (size_t)d * KPD;
        #pragma unroll
        for (int a = 0; a < 4; ++a) {
            int iq = g * 4 + a;
            #pragma unroll
            for (int j = 0; j < 16; ++j) rowp[17 + iq * 16 + j] = accq[a][j] * C2F;
            rowp[1 + iq] = accl[a] * 0.5f;
        }
        if (g == 0) rowp[0] = accc;
    } else {
        int lane = t - 256;
        float* rowp = kvp + base + (size_t)64 * KPD;
        for (int D = lane; D < DFEAT; D += 64) {
            float s = 0.f;
            if (D == 0) {
                s = 64.f;
            } else if (D < 17) {
                int i = D - 1;
                for (int tt = 0; tt < 64; ++tt) s += ks[tt][i];
                s *= 0.5f;
            } else {
                int e = D - 17, i = e >> 4, j = e & 15;
                for (int tt = 0; tt < 64; ++tt) s += ks[tt][i] * ks[tt][j];
                s *= C2F;
            }
            rowp[D] = s;
        }
    }
}

// ---------------------------------------------------------------------------
// Kernel 3: attention via MFMA, with the chunk-prefix scan FOLDED IN.
// Block (h,c): kvS = sum of kvp[h][c'<c] (fp32 accumulate -> bf16 LDS).
//  cross: acc[nt] += qf (LDS A-frag) x kvS (LDS B-frag), K=288
//  intra: S = QK^T -> poly/causal -> P -> acc[nt] += P x vT (row 64 = ones
//         completes the denominator in acc[4] col 0)
// ---------------------------------------------------------------------------
#define QFP 296   // qf LDS row stride
__global__ __launch_bounds__(256) void attn(
    const unsigned short* __restrict__ qb, const unsigned short* __restrict__ kb,
    const unsigned short* __restrict__ vb, const float* __restrict__ kvp,
    unsigned short* __restrict__ ybB) {
    int h = blockIdx.x & 15, c = blockIdx.x >> 4;
    int l0 = c * CHUNK;
    __shared__ __align__(16) unsigned short kvS[80][KVTP];   // 47360B
    __shared__ __align__(16) unsigned short qs[64][40];
    __shared__ __align__(16) unsigned short ksm[64][40];
    __shared__ __align__(16) unsigned short qf[64][QFP];
    __shared__ __align__(16) unsigned short vT[80][72];
    __shared__ __align__(16) unsigned short P[64][72];
    __shared__ float dens[64];
    int t = threadIdx.x, lane = t & 63, wave = t >> 6;
    int ml = lane & 15, q4 = lane >> 4;
    int m0 = wave * 16;

    // ---- fold the exclusive chunk-scan: kvS[dd][D] = sum_{c'<c} kvp[h][c'][dd][D]
    {
        const float* kvpb = kvp + (size_t)(h * NCHUNK) * 65 * KPD;
        const size_t cs = (size_t)65 * KPD;
        for (int e = t; e < 80 * 74; e += 256) {
            int dd = e / 74, q = e - dd * 74;
            int D = q * 4;
            float4 s = make_float4(0.f, 0.f, 0.f, 0.f);
            if (dd < 65 && D < DFEAT) {
                const float* p0 = kvpb + (size_t)dd * KPD + D;
                for (int cc = 0; cc < c; ++cc) {
                    float4 v = *(const float4*)(p0 + cc * cs);
                    s.x += v.x; s.y += v.y; s.z += v.z; s.w += v.w;
                }
                if (D + 1 >= DFEAT) s.y = 0.f;
                if (D + 2 >= DFEAT) s.z = 0.f;
                if (D + 3 >= DFEAT) s.w = 0.f;
            }
            unsigned short* p = &kvS[dd][D];
            p[0] = f2bf(s.x); p[1] = f2bf(s.y); p[2] = f2bf(s.z); p[3] = f2bf(s.w);
        }
    }

    // ---- stage q,k (zero-padded to K=32) and v^T (+ ones row 64)
    {
        int m = t >> 2, i4 = (t & 3) * 4;
        *(ushort4*)&qs[m][i4]  = *(const ushort4*)&qb[(size_t)(l0 + m) * 256 + h * 16 + i4];
        *(ushort4*)&ksm[m][i4] = *(const ushort4*)&kb[(size_t)(l0 + m) * 256 + h * 16 + i4];
        ushort4 z = {0, 0, 0, 0};
        *(ushort4*)&qs[m][16 + i4]  = z;
        *(ushort4*)&ksm[m][16 + i4] = z;
        int c0 = (t & 3) * 16;
        unsigned short tmp[16];
        #pragma unroll
        for (int u = 0; u < 4; ++u)
            *(ushort4*)&tmp[u * 4] = *(const ushort4*)&vb[(size_t)(l0 + m) * 1024 + h * 64 + c0 + u * 4];
        #pragma unroll
        for (int u = 0; u < 16; ++u) vT[c0 + u][m] = tmp[u];
    }
    if (t < 64) vT[64][t] = 0x3F80;   // 1.0 bf16
    __syncthreads();

    // ---- build qf[l][D] (bf16), zero-padded D in [273,296)
    {
        int l = t & 63, g = t >> 6;
        short8 v0 = *(const short8*)&qs[l][0];
        short8 v1 = *(const short8*)&qs[l][8];
        float qv[16];
        #pragma unroll
        for (int u = 0; u < 8; ++u) {
            qv[u]     = bf2f((unsigned short)v0[u]);
            qv[u + 8] = bf2f((unsigned short)v1[u]);
        }
        int lo = (g == 0) ? 0 : 69 + (g - 1) * 68;
        int hi = (g == 0) ? 69 : lo + 68;
        for (int D = lo; D < hi; ++D) {
            float val;
            if (D == 0) val = 1.f;
            else if (D < 17) val = qv[D - 1] * 0.5f;
            else { int e = D - 17; val = qv[e >> 4] * qv[e & 15] * C2F; }
            qf[l][D] = f2bf(val);
        }
        int zlo = 273 + g * 6, zhi = zlo + 6 > 296 ? 296 : zlo + 6;
        for (int D = zlo; D < zhi; ++D) qf[l][D] = 0;
    }

    // ---- intra scores: S = QK^T, poly+causal -> P
    {
        short8 a = *(const short8*)&qs[m0 + ml][q4 * 8];
        #pragma unroll
        for (int ntt = 0; ntt < 4; ++ntt) {
            short8 b = *(const short8*)&ksm[ntt * 16 + ml][q4 * 8];
            floatx4 sres = {0.f, 0.f, 0.f, 0.f};
            sres = MFMA(a, b, sres);
            #pragma unroll
            for (int r = 0; r < 4; ++r) {
                int tt = ntt * 16 + ml;
                int lrow = m0 + q4 * 4 + r;
                float s = sres[r];
                float p = (tt <= lrow) ? (1.f + 0.25f * s + 0.03125f * s * s) : 0.f;
                P[lrow][tt] = f2bf(p);
            }
        }
    }
    __syncthreads();   // kvS + qf + P complete

    // ---- cross term: qf x KV, all from LDS
    floatx4 acc[5];
    #pragma unroll
    for (int i = 0; i < 5; ++i) acc[i] = (floatx4){0.f, 0.f, 0.f, 0.f};
    #pragma unroll
    for (int k0 = 0; k0 < 288; k0 += 32) {
        short8 a = *(const short8*)&qf[m0 + ml][k0 + q4 * 8];
        #pragma unroll
        for (int nt = 0; nt < 5; ++nt) {
            short8 b = *(const short8*)&kvS[nt * 16 + ml][k0 + q4 * 8];
            acc[nt] = MFMA(a, b, acc[nt]);
        }
    }

    // ---- intra PV (vT row 64 = ones completes the denominator in acc[4])
    #pragma unroll
    for (int k0 = 0; k0 < 64; k0 += 32) {
        short8 a = *(const short8*)&P[m0 + ml][k0 + q4 * 8];
        #pragma unroll
        for (int nt = 0; nt < 5; ++nt) {
            short8 b = *(const short8*)&vT[nt * 16 + ml][k0 + q4 * 8];
            acc[nt] = MFMA(a, b, acc[nt]);
        }
    }
    if (ml == 0) {
        #pragma unroll
        for (int r = 0; r < 4; ++r) dens[m0 + q4 * 4 + r] = acc[4][r] + 1e-12f;
    }
    __syncthreads();

    // ---- epilogue: y = num/den -> bf16
    #pragma unroll
    for (int r = 0; r < 4; ++r) {
        int lrow = m0 + q4 * 4 + r;
        float dinv = 1.f / dens[lrow];
        unsigned short* yp = ybB + (size_t)(l0 + lrow) * 1024 + h * 64;
        #pragma unroll
        for (int nt = 0; nt < 4; ++nt)
            yp[nt * 16 + ml] = f2bf(acc[nt][r] * dinv);
    }
}

// ---------------------------------------------------------------------------
// Kernel 4: output projection, LDS-staged bf16 MFMA GEMM.
// out = y @ Wo^T (1024^3). A = ybB (bf16), B = Wo raw (dual dtype),
// output dtype per detector.
// ---------------------------------------------------------------------------
__global__ __launch_bounds__(256) void out_gemm(
    const unsigned short* __restrict__ A, const void* __restrict__ WoR,
    void* __restrict__ outv, const unsigned short* __restrict__ wqraw) {
    int fp32 = block_detect_fp32(wqraw);
    __shared__ __align__(16) unsigned short As[64][136];
    __shared__ __align__(16) unsigned short Bs[64][136];
    int nb = blockIdx.x, mb = blockIdx.y;
    int br0 = nb * 64;

    int t = threadIdx.x;
    int r = t >> 2, c0 = (t & 3) * 32;
    int wave = t >> 6, lane = t & 63;
    int ml = lane & 15, q4 = lane >> 4;
    int mq = (wave >> 1) * 32, nq = (wave & 1) * 32;
    floatx4 acc00 = {0.f,0.f,0.f,0.f}, acc01 = acc00, acc10 = acc00, acc11 = acc00;

    for (int k0 = 0; k0 < DMODEL; k0 += 128) {
        short8 av[4], bv[4];
        const unsigned short* Ap = A + (size_t)(mb * 64 + r) * DMODEL + k0 + c0;
        #pragma unroll
        for (int j = 0; j < 4; ++j) av[j] = *(const short8*)(Ap + j * 8);
        if (!fp32) {
            const unsigned short* Bp = (const unsigned short*)WoR + (size_t)(br0 + r) * DMODEL + k0 + c0;
            #pragma unroll
            for (int j = 0; j < 4; ++j) bv[j] = *(const short8*)(Bp + j * 8);
        } else {
            const float* Bp = (const float*)WoR + (size_t)(br0 + r) * DMODEL + k0 + c0;
            #pragma unroll
            for (int j = 0; j < 4; ++j) {
                #pragma unroll
                for (int u = 0; u < 8; ++u) bv[j][u] = (short)f2bf(Bp[j * 8 + u]);
            }
        }
        __syncthreads();
        #pragma unroll
        for (int j = 0; j < 4; ++j) {
            *(short8*)&As[r][c0 + j * 8] = av[j];
            *(short8*)&Bs[r][c0 + j * 8] = bv[j];
        }
        __syncthreads();
        #pragma unroll
        for (int kk = 0; kk < 4; ++kk) {
            short8 a0 = *(const short8*)&As[mq + ml][kk * 32 + q4 * 8];
            short8 a1 = *(const short8*)&As[mq + 16 + ml][kk * 32 + q4 * 8];
            short8 b0 = *(const short8*)&Bs[nq + ml][kk * 32 + q4 * 8];
            short8 b1 = *(const short8*)&Bs[nq + 16 + ml][kk * 32 + q4 * 8];
            acc00 = MFMA(a0, b0, acc00); acc01 = MFMA(a0, b1, acc01);
            acc10 = MFMA(a1, b0, acc10); acc11 = MFMA(a1, b1, acc11);
        }
    }
    #pragma unroll
    for (int mi = 0; mi < 2; ++mi) {
        #pragma unroll
        for (int ni = 0; ni < 2; ++ni) {
            floatx4 acc = mi == 0 ? (ni == 0 ? acc00 : acc01) : (ni == 0 ? acc10 : acc11);
            int n = nb * 64 + nq + ni * 16 + ml;
            #pragma unroll
            for (int r4 = 0; r4 < 4; ++r4) {
                int row = mb * 64 + mq + mi * 16 + q4 * 4 + r4;
                size_t idx = (size_t)row * 1024 + n;
                if (fp32) ((float*)outv)[idx] = acc[r4];
                else      ((unsigned short*)outv)[idx] = f2bf(acc[r4]);
            }
        }
    }
}

// ---------------------------------------------------------------------------
extern "C" void kernel_launch(void* const* d_in, const int* in_sizes, int n_in,
                              void* d_out, int out_size, void* d_ws, size_t ws_size,
                              hipStream_t stream) {
    unsigned short* us = (unsigned short*)d_ws;
    float* ws = (float*)d_ws;
    unsigned short* qbB = us + U_QB;
    unsigned short* kbB = us + U_KB;
    unsigned short* vbB = us + U_VB;
    unsigned short* ybB = us + U_YB;
    float* kvp = ws + F_KVP;
    size_t need = ((size_t)F_KVP + 4792320ull) * 4ull;
    if (ws_size < need) return;

    qkv_gemm<<<dim3(24, 16), 256, 0, stream>>>(d_in[0], d_in[1], d_in[2], d_in[3], qbB, kbB, vbB);
    chunk_kv<<<dim3(256), 320, 0, stream>>>(kbB, vbB, kvp);
    attn<<<dim3(256), 256, 0, stream>>>(qbB, kbB, vbB, kvp, ybB);
    out_gemm<<<dim3(16, 16), 256, 0, stream>>>(ybB, d_in[4], d_out, (const unsigned short*)d_in[1]);
}

// Round 7
// 152.285 us; speedup vs baseline: 1.4186x; 1.4186x over previous
//
#include <hip/hip_runtime.h>

// Problem constants
#define LSEQ 1024
#define DMODEL 1024
#define NHEADS 16
#define FDIM 16
#define HDIM 64
#define CHUNK 64
#define NCHUNK 16

typedef __attribute__((ext_vector_type(8))) short short8;   // 8 bf16 (4 VGPRs)
typedef __attribute__((ext_vector_type(4))) float floatx4;  // MFMA acc

__device__ __forceinline__ float bf2f(unsigned short u) {
    unsigned int x = ((unsigned int)u) << 16;
    return __builtin_bit_cast(float, x);
}
__device__ __forceinline__ unsigned short f2bf(float f) {
    unsigned int x = __builtin_bit_cast(unsigned int, f);
    unsigned int r = (x + 0x7fffu + ((x >> 16) & 1u)) >> 16;
    return (unsigned short)r;
}

// Per-block dtype detector: samples 1024 ushorts of Wq. bf16 data -> exponents
// cluster tightly (bad ~0%); fp32-as-ushort -> half the samples are uniform
// mantissa bits (bad ~30%+). Returns 1 if inputs are fp32.
__device__ __forceinline__ int block_detect_fp32(const unsigned short* wq) {
    __shared__ int cnt;
    if (threadIdx.x == 0) cnt = 0;
    __syncthreads();
    int bad = 0;
    for (int i = threadIdx.x; i < 1024; i += blockDim.x) {
        int e = (wq[i] >> 7) & 0xFF;
        if (e >= 143 || (e > 0 && e <= 80)) bad++;
    }
    if (bad) atomicAdd(&cnt, bad);
    __syncthreads();
    return cnt > 128;
}

// Workspace layout (ushort indices):
//   qbB @0        (262144)   bf16 q  [1024][256]
//   kbB @262144   (262144)   bf16 k  [1024][256]
//   vbB @524288   (1048576)  bf16 v  [1024][1024]
//   ybB @1572864  (1048576)  bf16 y  [1024][1024]
#define U_QB   0
#define U_KB   262144
#define U_VB   524288
#define U_YB   1572864

#define MFMA(a, b, c) __builtin_amdgcn_mfma_f32_16x16x32_bf16((a), (b), (c), 0, 0, 0)

// ---------------------------------------------------------------------------
// Kernel 1: QKV projection, LDS-staged bf16 MFMA GEMM, dual input dtype.
// C = hid @ [Wq;Wk;Wv]^T. 64x64 C-tile/block, BK=128, 8 K-iters.
// grid.x: 0..3 -> q, 4..7 -> k, 8..23 -> v. grid.y = row tile (16).
// ---------------------------------------------------------------------------
__global__ __launch_bounds__(256) void qkv_gemm(
    const void* __restrict__ hidR, const void* __restrict__ WqR,
    const void* __restrict__ WkR, const void* __restrict__ WvR,
    unsigned short* __restrict__ qb, unsigned short* __restrict__ kb,
    unsigned short* __restrict__ vb) {
    int fp32 = block_detect_fp32((const unsigned short*)WqR);
    __shared__ __align__(16) unsigned short As[64][136];
    __shared__ __align__(16) unsigned short Bs[64][136];
    int nb = blockIdx.x, mb = blockIdx.y;
    const void* Braw; unsigned short* Cout; int ldc, col0, br0;
    if (nb < 4)      { Braw = WqR; br0 = nb * 64;       Cout = qb; ldc = 256;  col0 = nb * 64; }
    else if (nb < 8) { Braw = WkR; br0 = (nb - 4) * 64; Cout = kb; ldc = 256;  col0 = (nb - 4) * 64; }
    else             { Braw = WvR; br0 = (nb - 8) * 64; Cout = vb; ldc = 1024; col0 = (nb - 8) * 64; }

    int t = threadIdx.x;
    int r = t >> 2, c0 = (t & 3) * 32;           // staging: row, col-segment
    int wave = t >> 6, lane = t & 63;
    int ml = lane & 15, q4 = lane >> 4;
    int mq = (wave >> 1) * 32, nq = (wave & 1) * 32;
    floatx4 acc00 = {0.f,0.f,0.f,0.f}, acc01 = acc00, acc10 = acc00, acc11 = acc00;

    for (int k0 = 0; k0 < DMODEL; k0 += 128) {
        short8 av[4], bv[4];
        if (!fp32) {
            const unsigned short* Ap = (const unsigned short*)hidR + (size_t)(mb * 64 + r) * DMODEL + k0 + c0;
            const unsigned short* Bp = (const unsigned short*)Braw + (size_t)(br0 + r) * DMODEL + k0 + c0;
            #pragma unroll
            for (int j = 0; j < 4; ++j) {
                av[j] = *(const short8*)(Ap + j * 8);
                bv[j] = *(const short8*)(Bp + j * 8);
            }
        } else {
            const float* Ap = (const float*)hidR + (size_t)(mb * 64 + r) * DMODEL + k0 + c0;
            const float* Bp = (const float*)Braw + (size_t)(br0 + r) * DMODEL + k0 + c0;
            #pragma unroll
            for (int j = 0; j < 4; ++j) {
                #pragma unroll
                for (int u = 0; u < 8; ++u) {
                    av[j][u] = (short)f2bf(Ap[j * 8 + u]);
                    bv[j][u] = (short)f2bf(Bp[j * 8 + u]);
                }
            }
        }
        __syncthreads();   // previous iter's LDS reads done
        #pragma unroll
        for (int j = 0; j < 4; ++j) {
            *(short8*)&As[r][c0 + j * 8] = av[j];
            *(short8*)&Bs[r][c0 + j * 8] = bv[j];
        }
        __syncthreads();
        #pragma unroll
        for (int kk = 0; kk < 4; ++kk) {
            short8 a0 = *(const short8*)&As[mq + ml][kk * 32 + q4 * 8];
            short8 a1 = *(const short8*)&As[mq + 16 + ml][kk * 32 + q4 * 8];
            short8 b0 = *(const short8*)&Bs[nq + ml][kk * 32 + q4 * 8];
            short8 b1 = *(const short8*)&Bs[nq + 16 + ml][kk * 32 + q4 * 8];
            acc00 = MFMA(a0, b0, acc00); acc01 = MFMA(a0, b1, acc01);
            acc10 = MFMA(a1, b0, acc10); acc11 = MFMA(a1, b1, acc11);
        }
    }
    #pragma unroll
    for (int mi = 0; mi < 2; ++mi) {
        #pragma unroll
        for (int ni = 0; ni < 2; ++ni) {
            floatx4 acc = mi == 0 ? (ni == 0 ? acc00 : acc01) : (ni == 0 ? acc10 : acc11);
            int nloc = nq + ni * 16 + ml;
            #pragma unroll
            for (int r4 = 0; r4 < 4; ++r4) {
                int row = mb * 64 + mq + mi * 16 + q4 * 4 + r4;
                Cout[(size_t)row * ldc + col0 + nloc] = f2bf(acc[r4]);
            }
        }
    }
}

// ---------------------------------------------------------------------------
// Kernel 2: flash-style quadratic polynomial attention. No feature map, no
// KV state: S(l,t) = 1 + (q.k)/4 + (q.k)^2/32, causal; y = S V / (S 1).
// Block (h, c): Q rows [64c, 64c+64), loop kv tiles j = 0..c.
//  S via MFMA (K=32 zero-padded), poly+mask -> P (wave-private LDS rows),
//  PV via MFMA with vT ones-row (n=64) accumulating the denominator.
// ---------------------------------------------------------------------------
__global__ __launch_bounds__(256) void flash_attn(
    const unsigned short* __restrict__ qb, const unsigned short* __restrict__ kb,
    const unsigned short* __restrict__ vb, unsigned short* __restrict__ ybB) {
    int h = blockIdx.x & 15, c = blockIdx.x >> 4;
    int l0 = c * CHUNK;
    __shared__ __align__(16) unsigned short qs[64][40];
    __shared__ __align__(16) unsigned short ksm[64][40];
    __shared__ __align__(16) unsigned short vT[80][72];   // rows 0..63 v^T, 64 ones
    __shared__ __align__(16) unsigned short P[64][72];
    int t = threadIdx.x, lane = t & 63, wave = t >> 6;
    int ml = lane & 15, q4 = lane >> 4;
    int m0 = wave * 16;

    // ---- one-time staging: q rows (zero-padded K=32), vT pad rows
    {
        int m = t >> 2, i4 = (t & 3) * 4;
        *(ushort4*)&qs[m][i4] = *(const ushort4*)&qb[(size_t)(l0 + m) * 256 + h * 16 + i4];
        ushort4 z = {0, 0, 0, 0};
        *(ushort4*)&qs[m][16 + i4]  = z;
        *(ushort4*)&ksm[m][16 + i4] = z;   // k pad, persists across tiles
    }
    if (t < 64) {
        vT[64][t] = 0x3F80;   // 1.0 bf16 (denominator row)
        #pragma unroll
        for (int i = 65; i < 80; ++i) vT[i][t] = 0;
    }

    floatx4 acc[5];
    #pragma unroll
    for (int i = 0; i < 5; ++i) acc[i] = (floatx4){0.f, 0.f, 0.f, 0.f};

    for (int j = 0; j <= c; ++j) {
        // ---- stage k_j (64x16) and v_j^T (64x64 -> vT)
        {
            int m = t >> 2, i4 = (t & 3) * 4;
            *(ushort4*)&ksm[m][i4] = *(const ushort4*)&kb[(size_t)(j * 64 + m) * 256 + h * 16 + i4];
            int cc = (t & 3) * 16;
            unsigned short tmp[16];
            #pragma unroll
            for (int u = 0; u < 4; ++u)
                *(ushort4*)&tmp[u * 4] = *(const ushort4*)&vb[(size_t)(j * 64 + m) * 1024 + h * 64 + cc + u * 4];
            #pragma unroll
            for (int u = 0; u < 16; ++u) vT[cc + u][m] = tmp[u];
        }
        __syncthreads();   // staging visible (also covers qs on first iter)

        // ---- scores S = q k^T (K=32, zero-padded), poly + causal -> P
        short8 aq = *(const short8*)&qs[m0 + ml][q4 * 8];
        bool diag = (j == c);
        #pragma unroll
        for (int nt = 0; nt < 4; ++nt) {
            short8 bk = *(const short8*)&ksm[nt * 16 + ml][q4 * 8];
            floatx4 s4 = {0.f, 0.f, 0.f, 0.f};
            s4 = MFMA(aq, bk, s4);
            int tt = nt * 16 + ml;
            #pragma unroll
            for (int r = 0; r < 4; ++r) {
                int lrow = m0 + q4 * 4 + r;
                float s = s4[r];
                float p = 1.f + 0.25f * s + 0.03125f * s * s;
                if (diag && tt > lrow) p = 0.f;
                P[lrow][tt] = f2bf(p);
            }
        }
        // P rows are wave-private (written rows m0..m0+15, read rows m0+ml):
        // no barrier needed before PV; compiler orders LDS within the wave.

        // ---- PV: acc[nt] += P x vT (nt=4 ones-row -> denominator in col 0)
        #pragma unroll
        for (int k0 = 0; k0 < 64; k0 += 32) {
            short8 ap = *(const short8*)&P[m0 + ml][k0 + q4 * 8];
            #pragma unroll
            for (int nt = 0; nt < 5; ++nt) {
                short8 bv = *(const short8*)&vT[nt * 16 + ml][k0 + q4 * 8];
                acc[nt] = MFMA(ap, bv, acc[nt]);
            }
        }
        __syncthreads();   // protect ksm/vT from next tile's staging
    }

    // ---- epilogue: den broadcast via shfl (lane (ml=0, q4) reg r holds den
    //      for row m0+q4*4+r); y = num/den -> bf16
    #pragma unroll
    for (int r = 0; r < 4; ++r) {
        float den = __shfl(acc[4][r], q4 * 16) + 1e-12f;
        float dinv = 1.f / den;
        int lrow = m0 + q4 * 4 + r;
        unsigned short* yp = ybB + (size_t)(l0 + lrow) * 1024 + h * 64;
        #pragma unroll
        for (int nt = 0; nt < 4; ++nt)
            yp[nt * 16 + ml] = f2bf(acc[nt][r] * dinv);
    }
}

// ---------------------------------------------------------------------------
// Kernel 3: output projection, LDS-staged bf16 MFMA GEMM.
// out = y @ Wo^T (1024^3). Output dtype per detector.
// ---------------------------------------------------------------------------
__global__ __launch_bounds__(256) void out_gemm(
    const unsigned short* __restrict__ A, const void* __restrict__ WoR,
    void* __restrict__ outv, const unsigned short* __restrict__ wqraw) {
    int fp32 = block_detect_fp32(wqraw);
    __shared__ __align__(16) unsigned short As[64][136];
    __shared__ __align__(16) unsigned short Bs[64][136];
    int nb = blockIdx.x, mb = blockIdx.y;
    int br0 = nb * 64;

    int t = threadIdx.x;
    int r = t >> 2, c0 = (t & 3) * 32;
    int wave = t >> 6, lane = t & 63;
    int ml = lane & 15, q4 = lane >> 4;
    int mq = (wave >> 1) * 32, nq = (wave & 1) * 32;
    floatx4 acc00 = {0.f,0.f,0.f,0.f}, acc01 = acc00, acc10 = acc00, acc11 = acc00;

    for (int k0 = 0; k0 < DMODEL; k0 += 128) {
        short8 av[4], bv[4];
        const unsigned short* Ap = A + (size_t)(mb * 64 + r) * DMODEL + k0 + c0;
        #pragma unroll
        for (int j = 0; j < 4; ++j) av[j] = *(const short8*)(Ap + j * 8);
        if (!fp32) {
            const unsigned short* Bp = (const unsigned short*)WoR + (size_t)(br0 + r) * DMODEL + k0 + c0;
            #pragma unroll
            for (int j = 0; j < 4; ++j) bv[j] = *(const short8*)(Bp + j * 8);
        } else {
            const float* Bp = (const float*)WoR + (size_t)(br0 + r) * DMODEL + k0 + c0;
            #pragma unroll
            for (int j = 0; j < 4; ++j) {
                #pragma unroll
                for (int u = 0; u < 8; ++u) bv[j][u] = (short)f2bf(Bp[j * 8 + u]);
            }
        }
        __syncthreads();
        #pragma unroll
        for (int j = 0; j < 4; ++j) {
            *(short8*)&As[r][c0 + j * 8] = av[j];
            *(short8*)&Bs[r][c0 + j * 8] = bv[j];
        }
        __syncthreads();
        #pragma unroll
        for (int kk = 0; kk < 4; ++kk) {
            short8 a0 = *(const short8*)&As[mq + ml][kk * 32 + q4 * 8];
            short8 a1 = *(const short8*)&As[mq + 16 + ml][kk * 32 + q4 * 8];
            short8 b0 = *(const short8*)&Bs[nq + ml][kk * 32 + q4 * 8];
            short8 b1 = *(const short8*)&Bs[nq + 16 + ml][kk * 32 + q4 * 8];
            acc00 = MFMA(a0, b0, acc00); acc01 = MFMA(a0, b1, acc01);
            acc10 = MFMA(a1, b0, acc10); acc11 = MFMA(a1, b1, acc11);
        }
    }
    #pragma unroll
    for (int mi = 0; mi < 2; ++mi) {
        #pragma unroll
        for (int ni = 0; ni < 2; ++ni) {
            floatx4 acc = mi == 0 ? (ni == 0 ? acc00 : acc01) : (ni == 0 ? acc10 : acc11);
            int n = nb * 64 + nq + ni * 16 + ml;
            #pragma unroll
            for (int r4 = 0; r4 < 4; ++r4) {
                int row = mb * 64 + mq + mi * 16 + q4 * 4 + r4;
                size_t idx = (size_t)row * 1024 + n;
                if (fp32) ((float*)outv)[idx] = acc[r4];
                else      ((unsigned short*)outv)[idx] = f2bf(acc[r4]);
            }
        }
    }
}

// ---------------------------------------------------------------------------
extern "C" void kernel_launch(void* const* d_in, const int* in_sizes, int n_in,
                              void* d_out, int out_size, void* d_ws, size_t ws_size,
                              hipStream_t stream) {
    unsigned short* us = (unsigned short*)d_ws;
    unsigned short* qbB = us + U_QB;
    unsigned short* kbB = us + U_KB;
    unsigned short* vbB = us + U_VB;
    unsigned short* ybB = us + U_YB;
    size_t need = (size_t)(U_YB + 1048576) * 2ull;
    if (ws_size < need) return;

    qkv_gemm<<<dim3(24, 16), 256, 0, stream>>>(d_in[0], d_in[1], d_in[2], d_in[3], qbB, kbB, vbB);
    flash_attn<<<dim3(256), 256, 0, stream>>>(qbB, kbB, vbB, ybB);
    out_gemm<<<dim3(16, 16), 256, 0, stream>>>(ybB, d_in[4], d_out, (const unsigned short*)d_in[1]);
}